// Round 4
// baseline (1059.319 us; speedup 1.0000x reference)
//
#include <hip/hip_runtime.h>

#define TT    512
#define HH    64
#define NB    4
#define NBLK  256
#define HP    72    // h^T pitch in f16

typedef _Float16 f16x8 __attribute__((ext_vector_type(8)));
typedef _Float16 f16x4 __attribute__((ext_vector_type(4)));
typedef float    f32x4 __attribute__((ext_vector_type(4)));

__device__ __forceinline__ float sigmoidf_(float x) {
    return 1.0f / (1.0f + __expf(-x));
}
__device__ __forceinline__ float tanhf_(float x) {
    return 1.0f - 2.0f / (1.0f + __expf(2.0f * x));
}

// r13: BARRIER-FREE two-wave design. 256 blocks x 128 threads (2 waves).
// Block owns 4 batches. Wave 0 computes ALL of layer 1 (M=256 rows = 4
// quadrants of r9's A-wave work); wave 1 computes ALL of layer 2 (fused
// K=128 over [h1; h2], 4 quadrants of r9's C-wave work).
//   - All intra-layer h exchange is IN-WAVE (LDS round trip, lgkmcnt only).
//   - The only cross-wave dep (h1 ring, depth 2) uses acquire/release LDS
//     flags: waves decouple in phase, so wave0's MFMA/LDS phases overlap
//     wave1's transcendental phases on the CU (r9's per-tick block barrier
//     phase-LOCKED the waves -> coincident stalls -> 2150 cy/tick).
// Per-quadrant fused loop (MFMA -> cell transpose -> pointwise) reuses r9's
// debugged indexing verbatim; summation order and conversion points are
// bit-identical to r9 -> same absmax class (3.9e-3).
// LESSONS: r8 cross-block handoff = 4x regression. r10 pointwise on 16
// lanes = 2x regression (transpose keeps 1 cell/lane/quadrant on 64 lanes).
// r12 extra blocks don't co-reside and can't shorten the chain anyway.
__global__ __launch_bounds__(128, 1) void lstm_mfma(
    const float* __restrict__ x,
    const float* __restrict__ w_ih0, const float* __restrict__ w_hh0,
    const float* __restrict__ b_ih0, const float* __restrict__ b_hh0,
    const float* __restrict__ w_ih1, const float* __restrict__ w_hh1,
    const float* __restrict__ b_ih1, const float* __restrict__ b_hh1,
    const float* __restrict__ w_out, const float* __restrict__ b_out,
    float* __restrict__ out)
{
    __shared__ __align__(16) _Float16 h1ring[2][16 * HP]; // h1 ring (wave0 -> wave1)
    __shared__ __align__(16) _Float16 h2buf[2][16 * HP];  // h2 hop (wave1 private)
    __shared__ __align__(16) _Float16 xsh[TT * 12];       // x [t][d][4] f16
    __shared__ __align__(16) f32x4 cellA[4][64];          // wave0 gate transpose
    __shared__ __align__(16) f32x4 cellC[4][64];          // wave1 gate transpose
    __shared__ __align__(16) float h2f[4 * 68];           // final h2 fp32
    __shared__ float lg[4][4];
    __shared__ int prog0;   // wave0 ticks completed
    __shared__ int cons1;   // wave1 ticks completed

    const int tid   = threadIdx.x;
    const int wave  = tid >> 6;          // 0 = layer 1, 1 = layer 2
    const int lane  = tid & 63;
    const int quad  = lane >> 4;
    const int n     = lane & 15;         // MFMA column = batch slot
    const int b0    = blockIdx.x * NB;

    const int cu    = lane >> 2;                      // unit-in-quadrant after transpose
    const int cb    = lane & 3;                       // batch after transpose
    const int rdslot = lane ^ ((lane >> 4) << 2);     // XOR-swizzled cell slot

    // ---- LDS init (both waves) ----
    for (int i = tid; i < 2 * 16 * HP; i += 128) {
        ((_Float16*)h1ring)[i] = (_Float16)0.f;
        ((_Float16*)h2buf)[i]  = (_Float16)0.f;
    }
    for (int i = tid; i < TT * 12; i += 128) {
        const int t = i / 12, rem = i - t * 12;
        const int d = rem >> 2, b = rem & 3;
        xsh[i] = (_Float16)x[(size_t)(b0 + b) * (TT * 3) + t * 3 + d];
    }
    if (tid == 0) { prog0 = 0; cons1 = 0; }
    __syncthreads();   // the ONLY block-wide barrier before the epilogue

    if (wave == 0) {
        // ================= wave 0 : layer 1 (all 4 quadrants) =================
        f16x8 whhf[4][4][2], axf[4][4];
        f32x4 biasf[4][4];
        #pragma unroll
        for (int wq = 0; wq < 4; ++wq) {
            #pragma unroll
            for (int g_ = 0; g_ < 4; ++g_) {
                const int arow = 16 * wq + 64 * g_ + n;
                const float* ph = w_hh0 + arow * HH;
                #pragma unroll
                for (int k0 = 0; k0 < 2; ++k0)
                    #pragma unroll
                    for (int j = 0; j < 8; ++j)
                        whhf[wq][g_][k0][j] = (_Float16)ph[quad * 8 + 32 * k0 + j];
                #pragma unroll
                for (int r = 0; r < 4; ++r) {
                    const int crow = 16 * wq + 64 * g_ + quad * 4 + r;
                    biasf[wq][g_][r] = b_ih0[crow] + b_hh0[crow];
                }
                f16x8 ax;
                #pragma unroll
                for (int j = 0; j < 8; ++j) ax[j] = (_Float16)0.f;
                if (quad == 0) {
                    ax[0] = (_Float16)w_ih0[arow * 3 + 0];
                    ax[1] = (_Float16)w_ih0[arow * 3 + 1];
                    ax[2] = (_Float16)w_ih0[arow * 3 + 2];
                }
                axf[wq][g_] = ax;
            }
        }
        float creg[4] = {0.f, 0.f, 0.f, 0.f};

        for (int t = 0; t < TT; ++t) {
            // ring slot t&1 held h1(t-2); wave1 consumed it once cons1 >= t-1
            if (t >= 2) {
                while (__hip_atomic_load(&cons1, __ATOMIC_ACQUIRE,
                                         __HIP_MEMORY_SCOPE_WORKGROUP) < t - 1) {}
            }
            f16x8 bx;
            #pragma unroll
            for (int j = 0; j < 8; ++j) bx[j] = (_Float16)0.f;
            if (quad == 0) {
                const _Float16* xp = xsh + t * 12 + (lane & 3);
                bx[0] = xp[0];
                bx[1] = xp[4];
                bx[2] = xp[8];
            }
            const _Float16* hsrc = h1ring[(t + 1) & 1];   // h1(t-1), own write
            const f16x8 bh0 = *(const f16x8*)(hsrc + n * HP + quad * 8);
            const f16x8 bh1 = *(const f16x8*)(hsrc + n * HP + quad * 8 + 32);
            #pragma unroll
            for (int wq = 0; wq < 4; ++wq) {
                f32x4 acc[4];
                #pragma unroll
                for (int g_ = 0; g_ < 4; ++g_) {
                    f32x4 a = __builtin_amdgcn_mfma_f32_16x16x32_f16(axf[wq][g_], bx, biasf[wq][g_], 0, 0, 0);
                    a = __builtin_amdgcn_mfma_f32_16x16x32_f16(whhf[wq][g_][0], bh0, a, 0, 0, 0);
                    a = __builtin_amdgcn_mfma_f32_16x16x32_f16(whhf[wq][g_][1], bh1, a, 0, 0, 0);
                    acc[g_] = a;
                }
                if (n < 4) {
                    #pragma unroll
                    for (int r = 0; r < 4; ++r) {
                        const int slot = (16 * quad + 4 * r + n) ^ (quad << 2);
                        f32x4 v = {acc[0][r], acc[1][r], acc[2][r], acc[3][r]};
                        cellA[wq][slot] = v;
                    }
                }
                const f32x4 gate = cellA[wq][rdslot];
                const float is = sigmoidf_(gate[0]);
                const float fs = sigmoidf_(gate[1]);
                const float gt = tanhf_(gate[2]);
                const float os = sigmoidf_(gate[3]);
                creg[wq] = fs * creg[wq] + is * gt;
                h1ring[t & 1][cb * HP + 16 * wq + cu] = (_Float16)(os * tanhf_(creg[wq]));
            }
            if (lane == 0)
                __hip_atomic_store(&prog0, t + 1, __ATOMIC_RELEASE,
                                   __HIP_MEMORY_SCOPE_WORKGROUP);
        }
    } else {
        // ================= wave 1 : layer 2 (all 4 quadrants) =================
        f16x8 wihf[4][4][2], whhf[4][4][2];
        f32x4 biasf[4][4];
        #pragma unroll
        for (int wq = 0; wq < 4; ++wq) {
            #pragma unroll
            for (int g_ = 0; g_ < 4; ++g_) {
                const int arow = 16 * wq + 64 * g_ + n;
                const float* pi = w_ih1 + arow * HH;
                const float* ph = w_hh1 + arow * HH;
                #pragma unroll
                for (int k0 = 0; k0 < 2; ++k0)
                    #pragma unroll
                    for (int j = 0; j < 8; ++j) {
                        wihf[wq][g_][k0][j] = (_Float16)pi[quad * 8 + 32 * k0 + j];
                        whhf[wq][g_][k0][j] = (_Float16)ph[quad * 8 + 32 * k0 + j];
                    }
                #pragma unroll
                for (int r = 0; r < 4; ++r) {
                    const int crow = 16 * wq + 64 * g_ + quad * 4 + r;
                    biasf[wq][g_][r] = b_ih1[crow] + b_hh1[crow];
                }
            }
        }
        float creg[4] = {0.f, 0.f, 0.f, 0.f};

        for (int t = 0; t < TT; ++t) {
            // need h1(t): wave0 publishes prog0 = t+1 after writing ring[t&1]
            while (__hip_atomic_load(&prog0, __ATOMIC_ACQUIRE,
                                     __HIP_MEMORY_SCOPE_WORKGROUP) < t + 1) {}
            const _Float16* h1src = h1ring[t & 1];        // h1(t)
            const _Float16* h2src = h2buf[(t + 1) & 1];   // h2(t-1), own write
            const f16x8 b10 = *(const f16x8*)(h1src + n * HP + quad * 8);
            const f16x8 b11 = *(const f16x8*)(h1src + n * HP + quad * 8 + 32);
            const f16x8 b20 = *(const f16x8*)(h2src + n * HP + quad * 8);
            const f16x8 b21 = *(const f16x8*)(h2src + n * HP + quad * 8 + 32);
            #pragma unroll
            for (int wq = 0; wq < 4; ++wq) {
                f32x4 acc[4];
                #pragma unroll
                for (int g_ = 0; g_ < 4; ++g_) {
                    f32x4 a = __builtin_amdgcn_mfma_f32_16x16x32_f16(wihf[wq][g_][0], b10, biasf[wq][g_], 0, 0, 0);
                    a = __builtin_amdgcn_mfma_f32_16x16x32_f16(wihf[wq][g_][1], b11, a, 0, 0, 0);
                    a = __builtin_amdgcn_mfma_f32_16x16x32_f16(whhf[wq][g_][0], b20, a, 0, 0, 0);
                    a = __builtin_amdgcn_mfma_f32_16x16x32_f16(whhf[wq][g_][1], b21, a, 0, 0, 0);
                    acc[g_] = a;
                }
                if (n < 4) {
                    #pragma unroll
                    for (int r = 0; r < 4; ++r) {
                        const int slot = (16 * quad + 4 * r + n) ^ (quad << 2);
                        f32x4 v = {acc[0][r], acc[1][r], acc[2][r], acc[3][r]};
                        cellC[wq][slot] = v;
                    }
                }
                const f32x4 gate = cellC[wq][rdslot];
                const float is = sigmoidf_(gate[0]);
                const float fs = sigmoidf_(gate[1]);
                const float gt = tanhf_(gate[2]);
                const float os = sigmoidf_(gate[3]);
                creg[wq] = fs * creg[wq] + is * gt;
                const float h = os * tanhf_(creg[wq]);
                h2buf[t & 1][cb * HP + 16 * wq + cu] = (_Float16)h;
                if (t == TT - 1) h2f[cb * 68 + 16 * wq + cu] = h;
            }
            if (lane == 0)
                __hip_atomic_store(&cons1, t + 1, __ATOMIC_RELEASE,
                                   __HIP_MEMORY_SCOPE_WORKGROUP);
        }
    }
    __syncthreads();

    // ---- epilogue: logits + softmax on fp32 h2 ----
    if (tid < 16) {
        const int b = tid & 3, o = tid >> 2;
        float acc = b_out[o];
        #pragma unroll
        for (int j = 0; j < HH; ++j)
            acc = fmaf(w_out[o * HH + j], h2f[b * 68 + j], acc);
        lg[b][o] = acc;
    }
    __syncthreads();
    if (tid < NB) {
        const int b = tid;
        const float l0 = lg[b][0], l1 = lg[b][1], l2 = lg[b][2], l3 = lg[b][3];
        const float m  = fmaxf(fmaxf(l0, l1), fmaxf(l2, l3));
        const float e0 = __expf(l0 - m), e1 = __expf(l1 - m);
        const float e2 = __expf(l2 - m), e3 = __expf(l3 - m);
        const float sum = 1.0f / (e0 + e1 + e2 + e3);
        out[(b0 + b) * 4 + 0] = e0 * sum;
        out[(b0 + b) * 4 + 1] = e1 * sum;
        out[(b0 + b) * 4 + 2] = e2 * sum;
        out[(b0 + b) * 4 + 3] = e3 * sum;
    }
}

extern "C" void kernel_launch(void* const* d_in, const int* in_sizes, int n_in,
                              void* d_out, int out_size, void* d_ws, size_t ws_size,
                              hipStream_t stream) {
    const float* x     = (const float*)d_in[0];
    const float* w_ih0 = (const float*)d_in[1];
    const float* w_hh0 = (const float*)d_in[2];
    const float* b_ih0 = (const float*)d_in[3];
    const float* b_hh0 = (const float*)d_in[4];
    const float* w_ih1 = (const float*)d_in[5];
    const float* w_hh1 = (const float*)d_in[6];
    const float* b_ih1 = (const float*)d_in[7];
    const float* b_hh1 = (const float*)d_in[8];
    const float* w_out = (const float*)d_in[9];
    const float* b_out = (const float*)d_in[10];
    float* out = (float*)d_out;

    hipLaunchKernelGGL(lstm_mfma, dim3(NBLK), dim3(128), 0, stream,
                       x, w_ih0, w_hh0, b_ih0, b_hh0,
                       w_ih1, w_hh1, b_ih1, b_hh1,
                       w_out, b_out, out);
}

// Round 5
// 470.113 us; speedup vs baseline: 2.2533x; 2.2533x over previous
//
#include <hip/hip_runtime.h>

#define TT    512
#define HH    64
#define NB    4
#define NBLK  256
#define HP    72    // h^T pitch in f16

typedef _Float16 f16x8 __attribute__((ext_vector_type(8)));
typedef _Float16 f16x4 __attribute__((ext_vector_type(4)));
typedef float    f32x4 __attribute__((ext_vector_type(4)));

__device__ __forceinline__ float sigmoidf_(float x) {
    return 1.0f / (1.0f + __expf(-x));
}
__device__ __forceinline__ float tanhf_(float x) {
    return 1.0f - 2.0f / (1.0f + __expf(2.0f * x));
}

// r14 = r9 (the proven 460us 8-wave kernel) + two chain-shorteners. 256
// blocks x 512 threads. Group A = waves 0-3 (layer 1), group C = waves 4-7
// (layer 2, fused K=128 over [h1; h2]). Wave w owns M-tiles {w,w+4,w+8,w+12};
// cell transpose -> 1 cell/lane pointwise on all 64 lanes. One barrier/tick.
// r14 changes ONLY:
//   (1) A: x-MFMA hoisted across the barrier — axacc[g] = mfma(axf, bx(t+1),
//       bias) computed in tick t's tail (xs is read-only after init). Post-
//       barrier A-chain = 2 MFMAs. Summation order (bias+x)+h0+h1 UNCHANGED
//       -> layer 1 bitwise identical to r9.
//   (2) C: 4-chain split into two 2-chains + fp32 add ((bias+ih.h1)+(hh.h2))
//       — 2 MFMA latencies off the longest path. Same reorder measured
//       absmax 9.8e-4 inside r10.
// LESSONS: r10 pointwise on 16 lanes = 2x. r12 extra blocks don't co-reside.
// r13 2-wave/4-quadrant = issue-bound on 2 SIMDs, 2.2x. r8 cross-block
// handoff = 4x. Keep r9's 8-wave 1-barrier shape.
__global__ __launch_bounds__(512) void lstm_mfma(
    const float* __restrict__ x,
    const float* __restrict__ w_ih0, const float* __restrict__ w_hh0,
    const float* __restrict__ b_ih0, const float* __restrict__ b_hh0,
    const float* __restrict__ w_ih1, const float* __restrict__ w_hh1,
    const float* __restrict__ b_ih1, const float* __restrict__ b_hh1,
    const float* __restrict__ w_out, const float* __restrict__ b_out,
    float* __restrict__ out)
{
    __shared__ __align__(16) _Float16 h1T[2][16 * HP];  // h1^T [batch][unit] f16
    __shared__ __align__(16) _Float16 h2T[2][16 * HP];  // h2^T
    __shared__ float xs[TT * 12];                       // x [t][d][4] fp32
    __shared__ __align__(16) f32x4 cellA[4][64];        // A gate transpose
    __shared__ __align__(16) f32x4 cellC[4][64];        // C gate transpose
    __shared__ __align__(16) float h2f[16 * 68];        // final h2 fp32
    __shared__ float lg[NB][4];

    const int tid   = threadIdx.x;
    const int group = tid >> 8;          // 0 = A (layer 1), 1 = C (layer 2)
    const int w     = (tid >> 6) & 3;    // wave-in-group
    const int lane  = tid & 63;
    const int quad  = lane >> 4;
    const int n     = lane & 15;         // MFMA column = batch slot
    const int b0    = blockIdx.x * NB;

    const int cu    = lane >> 2;                      // unit after transpose
    const int cb    = lane & 3;                       // batch after transpose
    const int rdslot = lane ^ ((lane >> 4) << 2);     // XOR-swizzled cell slot

    // ---- persistent weight fragments ----
    f16x8 whh[4][2], wih[4][2], axf[4];
    f32x4 biasf[4];
    #pragma unroll
    for (int g_ = 0; g_ < 4; ++g_) {
        const int arow = 16 * w + 64 * g_ + n;        // A-frag row m = lane&15
        const float* ph = (group == 0) ? (w_hh0 + arow * HH) : (w_hh1 + arow * HH);
        const float* pi = w_ih1 + arow * HH;
        #pragma unroll
        for (int k0 = 0; k0 < 2; ++k0) {
            #pragma unroll
            for (int j = 0; j < 8; ++j) {
                whh[g_][k0][j] = (_Float16)ph[quad * 8 + 32 * k0 + j];
                wih[g_][k0][j] = (group == 1) ? (_Float16)pi[quad * 8 + 32 * k0 + j]
                                              : (_Float16)0.f;
            }
        }
        #pragma unroll
        for (int r = 0; r < 4; ++r) {                 // C/D row = quad*4 + r
            const int crow = 16 * w + 64 * g_ + quad * 4 + r;
            biasf[g_][r] = (group == 0) ? (b_ih0[crow] + b_hh0[crow])
                                        : (b_ih1[crow] + b_hh1[crow]);
        }
        f16x8 ax;
        #pragma unroll
        for (int j = 0; j < 8; ++j) ax[j] = (_Float16)0.f;
        if (group == 0 && quad == 0) {                // K=3 x-transform
            ax[0] = (_Float16)w_ih0[arow * 3 + 0];
            ax[1] = (_Float16)w_ih0[arow * 3 + 1];
            ax[2] = (_Float16)w_ih0[arow * 3 + 2];
        }
        axf[g_] = ax;
    }

    // ---- LDS init ----
    for (int i = tid; i < 1152; i += 512) {
        ((int*)h1T)[i] = 0;
        ((int*)h2T)[i] = 0;
    }
    for (int i = tid; i < TT * 12; i += 512) {
        const int t = i / 12, rem = i - t * 12;
        const int d = rem >> 2, b = rem & 3;
        xs[i] = x[(size_t)(b0 + b) * (TT * 3) + t * 3 + d];
    }
    __syncthreads();

    float creg = 0.f;    // A: c1 of (unit 16w+cu, batch cb); C: c2 of same

    // A-group: pre-compute axacc for t=0 (bias + W_ih0 x(0))
    f32x4 axacc[4];
    if (group == 0) {
        f16x8 bx;
        #pragma unroll
        for (int j = 0; j < 8; ++j) bx[j] = (_Float16)0.f;
        if (quad == 0) {
            const float* xp = xs + 0 * 12 + (lane & 3);
            bx[0] = (_Float16)xp[0];
            bx[1] = (_Float16)xp[4];
            bx[2] = (_Float16)xp[8];
        }
        #pragma unroll
        for (int g_ = 0; g_ < 4; ++g_)
            axacc[g_] = __builtin_amdgcn_mfma_f32_16x16x32_f16(axf[g_], bx, biasf[g_], 0, 0, 0);
    }

    for (int t = 0; t <= TT; ++t) {
        if (group == 0) {
            if (t < TT) {
                const _Float16* hsrc = h1T[(t + 1) & 1];
                const f16x8 bh0 = *(const f16x8*)(hsrc + n * HP + quad * 8);
                const f16x8 bh1 = *(const f16x8*)(hsrc + n * HP + quad * 8 + 32);
                f32x4 acc[4];
                #pragma unroll
                for (int g_ = 0; g_ < 4; ++g_) {
                    f32x4 a = __builtin_amdgcn_mfma_f32_16x16x32_f16(whh[g_][0], bh0, axacc[g_], 0, 0, 0);
                    a = __builtin_amdgcn_mfma_f32_16x16x32_f16(whh[g_][1], bh1, a, 0, 0, 0);
                    acc[g_] = a;
                }
                if (n < 4) {
                    #pragma unroll
                    for (int r = 0; r < 4; ++r) {
                        const int slot = (16 * quad + 4 * r + n) ^ (quad << 2);
                        f32x4 v = {acc[0][r], acc[1][r], acc[2][r], acc[3][r]};
                        cellA[w][slot] = v;
                    }
                }
                const f32x4 gate = cellA[w][rdslot];
                const float is = sigmoidf_(gate[0]);
                const float fs = sigmoidf_(gate[1]);
                const float gt = tanhf_(gate[2]);
                const float os = sigmoidf_(gate[3]);
                creg = fs * creg + is * gt;
                h1T[t & 1][cb * HP + 16 * w + cu] = (_Float16)(os * tanhf_(creg));
                // ---- tail: hoist next tick's x-MFMA across the barrier ----
                if (t + 1 < TT) {
                    f16x8 bx;
                    #pragma unroll
                    for (int j = 0; j < 8; ++j) bx[j] = (_Float16)0.f;
                    if (quad == 0) {
                        const float* xp = xs + (t + 1) * 12 + (lane & 3);
                        bx[0] = (_Float16)xp[0];
                        bx[1] = (_Float16)xp[4];
                        bx[2] = (_Float16)xp[8];
                    }
                    #pragma unroll
                    for (int g_ = 0; g_ < 4; ++g_)
                        axacc[g_] = __builtin_amdgcn_mfma_f32_16x16x32_f16(axf[g_], bx, biasf[g_], 0, 0, 0);
                }
            }
        } else {
            if (t >= 1) {
                // fused K=128 matvec over [h1(t-1); h2(t-2)], two 2-chains
                const _Float16* h1src = h1T[(t + 1) & 1];
                const _Float16* h2src = h2T[(t + 1) & 1];
                const f16x8 b10 = *(const f16x8*)(h1src + n * HP + quad * 8);
                const f16x8 b11 = *(const f16x8*)(h1src + n * HP + quad * 8 + 32);
                const f16x8 b20 = *(const f16x8*)(h2src + n * HP + quad * 8);
                const f16x8 b21 = *(const f16x8*)(h2src + n * HP + quad * 8 + 32);
                const f32x4 zero = {0.f, 0.f, 0.f, 0.f};
                f32x4 acc[4];
                #pragma unroll
                for (int g_ = 0; g_ < 4; ++g_) {
                    f32x4 p = __builtin_amdgcn_mfma_f32_16x16x32_f16(wih[g_][0], b10, biasf[g_], 0, 0, 0);
                    p = __builtin_amdgcn_mfma_f32_16x16x32_f16(wih[g_][1], b11, p, 0, 0, 0);
                    f32x4 q4 = __builtin_amdgcn_mfma_f32_16x16x32_f16(whh[g_][0], b20, zero, 0, 0, 0);
                    q4 = __builtin_amdgcn_mfma_f32_16x16x32_f16(whh[g_][1], b21, q4, 0, 0, 0);
                    acc[g_] = p + q4;
                }
                if (n < 4) {
                    #pragma unroll
                    for (int r = 0; r < 4; ++r) {
                        const int slot = (16 * quad + 4 * r + n) ^ (quad << 2);
                        f32x4 v = {acc[0][r], acc[1][r], acc[2][r], acc[3][r]};
                        cellC[w][slot] = v;
                    }
                }
                const f32x4 gate = cellC[w][rdslot];
                const float is = sigmoidf_(gate[0]);
                const float fs = sigmoidf_(gate[1]);
                const float gt = tanhf_(gate[2]);
                const float os = sigmoidf_(gate[3]);
                creg = fs * creg + is * gt;
                const float h = os * tanhf_(creg);
                h2T[t & 1][cb * HP + 16 * w + cu] = (_Float16)h;   // h2(t-1)
                if (t == TT) h2f[cb * 68 + 16 * w + cu] = h;       // h2(TT-1) fp32
            }
        }
        __syncthreads();
    }

    // ---- epilogue: logits + softmax on fp32 h2 ----
    if (tid < 16) {
        const int b = tid & 3, o = tid >> 2;
        float acc = b_out[o];
        #pragma unroll
        for (int j = 0; j < HH; ++j)
            acc = fmaf(w_out[o * HH + j], h2f[b * 68 + j], acc);
        lg[b][o] = acc;
    }
    __syncthreads();
    if (tid < NB) {
        const int b = tid;
        const float l0 = lg[b][0], l1 = lg[b][1], l2 = lg[b][2], l3 = lg[b][3];
        const float m  = fmaxf(fmaxf(l0, l1), fmaxf(l2, l3));
        const float e0 = __expf(l0 - m), e1 = __expf(l1 - m);
        const float e2 = __expf(l2 - m), e3 = __expf(l3 - m);
        const float sum = 1.0f / (e0 + e1 + e2 + e3);
        out[(b0 + b) * 4 + 0] = e0 * sum;
        out[(b0 + b) * 4 + 1] = e1 * sum;
        out[(b0 + b) * 4 + 2] = e2 * sum;
        out[(b0 + b) * 4 + 3] = e3 * sum;
    }
}

extern "C" void kernel_launch(void* const* d_in, const int* in_sizes, int n_in,
                              void* d_out, int out_size, void* d_ws, size_t ws_size,
                              hipStream_t stream) {
    const float* x     = (const float*)d_in[0];
    const float* w_ih0 = (const float*)d_in[1];
    const float* w_hh0 = (const float*)d_in[2];
    const float* b_ih0 = (const float*)d_in[3];
    const float* b_hh0 = (const float*)d_in[4];
    const float* w_ih1 = (const float*)d_in[5];
    const float* w_hh1 = (const float*)d_in[6];
    const float* b_ih1 = (const float*)d_in[7];
    const float* b_hh1 = (const float*)d_in[8];
    const float* w_out = (const float*)d_in[9];
    const float* b_out = (const float*)d_in[10];
    float* out = (float*)d_out;

    hipLaunchKernelGGL(lstm_mfma, dim3(NBLK), dim3(512), 0, stream,
                       x, w_ih0, w_hh0, b_ih0, b_hh0,
                       w_ih1, w_hh1, b_ih1, b_hh1,
                       w_out, b_out, out);
}